// Round 8
// baseline (27.162 us; speedup 1.0000x reference)
//
#include <hip/hip_runtime.h>

#define NB 64
#define NT 50
#define NC 80

#define S13 (NB*3*13*13)   /* 32448  */
#define S26 (NB*3*26*26)   /* 129792 */
#define S52 (NB*3*52*52)   /* 519168 */

#define PB_BLOCKS 256               /* 4 sparse blocks per image */
#define DN_BLOCKS 1792              /* R8: 768 -> 1792 (dense BW scaling test) */
#define NBLK (PB_BLOCKS + DN_BLOCKS) /* 2048 */

// transposed per-block partials: row-contiguous for a coalesced final reduce.
// Fully overwritten every call; kernel boundary provides visibility (no fences!
// R4 showed per-block __threadfence costs ~100us on non-coherent XCD L2s).
__device__ float g_partT[48][NBLK];

// accumulator slots (per level, base = lvl*16)
#define A_SPX 0   // sum softplus(zx) over all cells
#define A_SPY 1
#define A_SW2 2   // sum pw^2
#define A_SH2 3
#define A_SPC 4   // sum softplus(zc)
#define A_TXZ 5   // sum tx*zx at winner cells
#define A_TYZ 6
#define A_TW  7   // sum (tw^2 - 2*pw*tw)
#define A_TH  8
#define A_ZC  9   // sum zc at winner cells
#define A_SSC 10  // sum (2 - w*h) at winner cells
#define A_NOB 11  // count distinct assigned cells
#define A_CSP 12  // sum_c softplus(zcls) at winner cells
#define A_CZ  13  // sum zcls[cell, cls] per assigned target

// Polynomial softplus: inputs are 0.1*N(0,1) -> |z| <= ~0.6 over 10.2M samples.
// Even-series softplus(z) = ln2 + z/2 + z^2/8 - z^4/192 + z^6/2880, |err|<2e-6
// on [-0.92,0.92]; exact-form fallback beyond (effectively never taken).
__device__ __forceinline__ float softplusf(float z){
    float u = z*z;
    if (fabsf(z) < 0.92f)
        return 0.6931471805599453f + 0.5f*z
             + u*(0.125f + u*(-5.2083333e-3f + u*3.4722222e-4f));
    return fmaxf(z, 0.f) + __logf(1.f + __expf(-fabsf(z)));
}

struct TDec {
    int lvl, a, gx, gy, F, FF, off;
    float tx, ty, tw, th, w, h;
    int cls;
};

__device__ __forceinline__ TDec decode_target(const float* __restrict__ tgt, int b, int n){
    const float aw[9] = {116.f/416.f,156.f/416.f,373.f/416.f, 30.f/416.f, 62.f/416.f,
                          59.f/416.f, 10.f/416.f, 16.f/416.f, 33.f/416.f};
    const float ah[9] = { 90.f/416.f,198.f/416.f,326.f/416.f, 61.f/416.f, 45.f/416.f,
                         119.f/416.f, 13.f/416.f, 30.f/416.f, 23.f/416.f};
    const float* t = tgt + (b*NT + n)*5;
    float cx = t[0], cy = t[1], w = t[2], h = t[3];
    TDec d;
    d.cls = (int)t[4];
    d.w = w; d.h = h;
    float wh = w*h;
    int best = 0; float bi = -1.f, baw = aw[0], bah = ah[0];
    #pragma unroll
    for (int k = 0; k < 9; ++k){
        float inter = fminf(w, aw[k]) * fminf(h, ah[k]);
        float uni   = wh + aw[k]*ah[k] - inter;
        float r     = inter / uni;
        if (r > bi){ bi = r; best = k; baw = aw[k]; bah = ah[k]; }  // first-max wins
    }
    d.lvl = best / 3;
    d.a   = best - d.lvl*3;
    d.F   = (d.lvl==0) ? 13 : (d.lvl==1 ? 26 : 52);
    d.FF  = d.F * d.F;
    d.off = (d.lvl==0) ? 0 : (d.lvl==1 ? S13 : (S13+S26));
    float fx = cx * (float)d.F, fy = cy * (float)d.F;
    d.gx = (int)floorf(fx); d.gy = (int)floorf(fy);
    d.tx = fx - (float)d.gx; d.ty = fy - (float)d.gy;
    d.tw = logf(w / baw);   // 3200 evals total — precise is fine
    d.th = logf(h / bah);
    return d;
}

// ---- dense helpers: sum softplus/square over channels 0..4 of every anchor block ----
template<int FF, int LVL>
__device__ __forceinline__ void dense_scalar(const float* __restrict__ feat, int gb, float* sacc){
    constexpr int elems = NB*3*5*FF;
    constexpr int cFF = 5*FF;
    float s0=0.f,s1=0.f,s2=0.f,s3=0.f,s4=0.f;
    for (int i = gb*256 + (int)threadIdx.x; i < elems; i += DN_BLOCKS*256){
        int ba = i / cFF;              // compile-time divisor -> mul/shift
        int r  = i - ba*cFF;
        int c  = r / FF;
        float v = feat[ba*85*FF + r];
        if      (c == 0) s0 += softplusf(v);
        else if (c == 1) s1 += softplusf(v);
        else if (c == 2) s2 += v*v;
        else if (c == 3) s3 += v*v;
        else             s4 += softplusf(v);
    }
    float vals[5] = {s0,s1,s2,s3,s4};
    int lane = threadIdx.x & 63;
    #pragma unroll
    for (int k = 0; k < 5; ++k){
        float v = vals[k];
        #pragma unroll
        for (int o = 32; o > 0; o >>= 1) v += __shfl_down(v, o);
        if (lane == 0) atomicAdd(&sacc[LVL*16 + k], v);
    }
}

template<int FF, int LVL>
__device__ __forceinline__ void dense_vec4(const float* __restrict__ feat, int gb, float* sacc){
    static_assert(FF % 4 == 0, "");
    constexpr int e4   = NB*3*5*FF/4;
    constexpr int cFF4 = 5*FF/4;
    constexpr int qFF  = FF/4;
    const float4* f4 = (const float4*)feat;
    float s0=0.f,s1=0.f,s2=0.f,s3=0.f,s4=0.f;
    for (int i = gb*256 + (int)threadIdx.x; i < e4; i += DN_BLOCKS*256){
        int ba = i / cFF4;
        int r  = i - ba*cFF4;
        int c  = r / qFF;
        float4 v = f4[ba*(85*FF/4) + r];
        if (c == 2 || c == 3){
            float sq = v.x*v.x + v.y*v.y + v.z*v.z + v.w*v.w;
            if (c == 2) s2 += sq; else s3 += sq;
        } else {
            float sp = softplusf(v.x)+softplusf(v.y)+softplusf(v.z)+softplusf(v.w);
            if (c == 0) s0 += sp; else if (c == 1) s1 += sp; else s4 += sp;
        }
    }
    float vals[5] = {s0,s1,s2,s3,s4};
    int lane = threadIdx.x & 63;
    #pragma unroll
    for (int k = 0; k < 5; ++k){
        float v = vals[k];
        #pragma unroll
        for (int o = 32; o > 0; o >>= 1) v += __shfl_down(v, o);
        if (lane == 0) atomicAdd(&sacc[LVL*16 + k], v);
    }
}

__global__ __launch_bounds__(256) void k_fused(const float* __restrict__ p13,
                                              const float* __restrict__ p26,
                                              const float* __restrict__ p52,
                                              const float* __restrict__ tgt){
    __shared__ float sacc[48];
    int tid = threadIdx.x;
    if (tid < 48) sacc[tid] = 0.f;
    __syncthreads();

    if (blockIdx.x < PB_BLOCKS){
        // ---------- sparse path: 4 blocks per image ----------
        __shared__ int   skey[NT];
        __shared__ int   scb [NT];
        __shared__ int   slvl[NT];
        __shared__ int   scls[NT];
        __shared__ float sf  [NT][6];   // tx,ty,tw,th,w,h
        __shared__ unsigned char swin[NT];
        int b = blockIdx.x >> 2, q = blockIdx.x & 3;
        if (tid < NT){
            TDec d = decode_target(tgt, b, tid);
            int flat = ((b*3 + d.a)*d.F + d.gy)*d.F + d.gx;
            skey[tid] = d.off + flat;
            scb [tid] = ((b*3 + d.a)*85)*d.FF + d.gy*d.F + d.gx;
            slvl[tid] = d.lvl; scls[tid] = d.cls;
            sf[tid][0]=d.tx; sf[tid][1]=d.ty; sf[tid][2]=d.tw;
            sf[tid][3]=d.th; sf[tid][4]=d.w;  sf[tid][5]=d.h;
        }
        __syncthreads();
        if (tid < NT){
            int k = skey[tid]; unsigned char wn = 1;
            for (int m = tid+1; m < NT; ++m) if (skey[m] == k){ wn = 0; break; }  // last-writer wins
            swin[tid] = wn;
        }
        __syncthreads();

        int lane = tid & 63, wv = tid >> 6;
        int n0 = q*13, n1 = (n0+13 < NT) ? n0+13 : NT;
        for (int n = n0 + wv; n < n1; n += 4){
            int lvl = slvl[n];
            const float* feat = (lvl==0) ? p13 : (lvl==1 ? p26 : p52);
            int FF = (lvl==0) ? 169 : (lvl==1 ? 676 : 2704);
            int cb = scb[n];
            int cls = scls[n];
            if (!swin[n]){
                if (lane == 0){
                    float zcl = feat[cb + (5+cls)*FF];   // loser still sets cls_t at winner cell
                    atomicAdd(&sacc[lvl*16 + A_CZ], zcl);
                }
                continue;
            }
            // 85 channels at stride FF: ch=lane (0..63) + ch=64+lane (lane<21)
            float v1 = feat[cb + lane*FF];
            float v2 = (lane < 21) ? feat[cb + (64+lane)*FF] : 0.f;
            float csum = (lane >= 5) ? softplusf(v1) : 0.f;
            if (lane < 21) csum += softplusf(v2);
            #pragma unroll
            for (int o = 32; o > 0; o >>= 1) csum += __shfl_down(csum, o);
            float zx = __shfl(v1, 0), zy = __shfl(v1, 1);
            float pw = __shfl(v1, 2), ph = __shfl(v1, 3), zc = __shfl(v1, 4);
            int ch = 5 + cls;
            float zcl = (ch < 64) ? __shfl(v1, ch) : __shfl(v2, ch - 64);
            if (lane == 0){
                float* acc = &sacc[lvl*16];
                float tx=sf[n][0], ty=sf[n][1], tw=sf[n][2], th=sf[n][3], w=sf[n][4], h=sf[n][5];
                atomicAdd(&acc[A_CZ ], zcl);
                atomicAdd(&acc[A_TXZ], tx*zx);
                atomicAdd(&acc[A_TYZ], ty*zy);
                atomicAdd(&acc[A_TW ], tw*tw - 2.f*pw*tw);
                atomicAdd(&acc[A_TH ], th*th - 2.f*ph*th);
                atomicAdd(&acc[A_ZC ], zc);
                atomicAdd(&acc[A_SSC], 2.f - w*h);
                atomicAdd(&acc[A_NOB], 1.f);
                atomicAdd(&acc[A_CSP], csum);
            }
        }
    } else {
        // ---------- dense path ----------
        int gb = blockIdx.x - PB_BLOCKS;
        dense_scalar< 169,0>(p13, gb, sacc);
        dense_vec4  < 676,1>(p26, gb, sacc);
        dense_vec4  <2704,2>(p52, gb, sacc);
    }
    __syncthreads();
    if (tid < 48) g_partT[tid][blockIdx.x] = sacc[tid];   // plain store; kernel boundary = fence
}

__global__ __launch_bounds__(256) void k_final(float* __restrict__ out){
    __shared__ float bins[48];
    int lane = threadIdx.x & 63, wv = threadIdx.x >> 6;   // 4 waves
    for (int slot = wv; slot < 48; slot += 4){
        float s = 0.f;
        #pragma unroll
        for (int k = 0; k < NBLK/64; ++k) s += g_partT[slot][k*64 + lane];  // coalesced
        #pragma unroll
        for (int o = 32; o > 0; o >>= 1) s += __shfl_down(s, o);
        if (lane == 0) bins[slot] = s;
    }
    __syncthreads();
    if (threadIdx.x == 0){
        float total = 0.f, ntot = 0.f;
        const int sizes[3] = {S13, S26, S52};
        #pragma unroll
        for (int l = 0; l < 3; ++l){
            const float* a = &bins[l*16];
            float size = (float)sizes[l];
            float ssc  = a[A_SSC];
            float lx = (a[A_SPX] - a[A_TXZ]) / size * ssc;
            float ly = (a[A_SPY] - a[A_TYZ]) / size * ssc;
            float lw = (a[A_SW2] + a[A_TW ]) / size * (0.5f*ssc);
            float lh = (a[A_SH2] + a[A_TH ]) / size * (0.5f*ssc);
            float lc = a[A_SPC] - a[A_ZC];       // bce_c*(sum obj + sum noobj) == bce_c*size
            float lcls = (a[A_CSP] - a[A_CZ]) / (a[A_NOB]*(float)NC);
            total += lx + ly + lw + lh + lc + 5.f*lcls;
            ntot  += a[A_NOB];
        }
        out[0] = total / ntot;
    }
}

extern "C" void kernel_launch(void* const* d_in, const int* in_sizes, int n_in,
                              void* d_out, int out_size, void* d_ws, size_t ws_size,
                              hipStream_t stream){
    const float* p13 = (const float*)d_in[0];
    const float* p26 = (const float*)d_in[1];
    const float* p52 = (const float*)d_in[2];
    const float* tgt = (const float*)d_in[3];
    float* out = (float*)d_out;

    k_fused<<<NBLK, 256, 0, stream>>>(p13, p26, p52, tgt);
    k_final<<<1, 256, 0, stream>>>(out);
}

// Round 9
// 25.320 us; speedup vs baseline: 1.0727x; 1.0727x over previous
//
#include <hip/hip_runtime.h>

#define NB 64
#define NT 50
#define NC 80

#define S13 (NB*3*13*13)   /* 32448  */
#define S26 (NB*3*26*26)   /* 129792 */
#define S52 (NB*3*52*52)   /* 519168 */

#define PB_BLOCKS 256               /* 4 sparse blocks per image */
#define DN_BLOCKS 768               /* R9: revert to R7 optimum (1024 total) */
#define NBLK (PB_BLOCKS + DN_BLOCKS)

// transposed per-block partials: row-contiguous for a coalesced final reduce.
// Fully overwritten every call; kernel boundary provides visibility (no fences!
// R4 showed per-block __threadfence costs ~100us on non-coherent XCD L2s).
__device__ float g_partT[48][NBLK];

// accumulator slots (per level, base = lvl*16)
#define A_SPX 0   // sum softplus(zx) over all cells
#define A_SPY 1
#define A_SW2 2   // sum pw^2
#define A_SH2 3
#define A_SPC 4   // sum softplus(zc)
#define A_TXZ 5   // sum tx*zx at winner cells
#define A_TYZ 6
#define A_TW  7   // sum (tw^2 - 2*pw*tw)
#define A_TH  8
#define A_ZC  9   // sum zc at winner cells
#define A_SSC 10  // sum (2 - w*h) at winner cells
#define A_NOB 11  // count distinct assigned cells
#define A_CSP 12  // sum_c softplus(zcls) at winner cells
#define A_CZ  13  // sum zcls[cell, cls] per assigned target

// Polynomial softplus: inputs are 0.1*N(0,1) -> |z| <= ~0.6 over 10.2M samples.
// Even-series softplus(z) = ln2 + z/2 + z^2/8 - z^4/192 + z^6/2880, |err|<2e-6
// on [-0.92,0.92]; exact-form fallback beyond (effectively never taken).
__device__ __forceinline__ float softplusf(float z){
    float u = z*z;
    if (fabsf(z) < 0.92f)
        return 0.6931471805599453f + 0.5f*z
             + u*(0.125f + u*(-5.2083333e-3f + u*3.4722222e-4f));
    return fmaxf(z, 0.f) + __logf(1.f + __expf(-fabsf(z)));
}

struct TDec {
    int lvl, a, gx, gy, F, FF, off;
    float tx, ty, tw, th, w, h;
    int cls;
};

__device__ __forceinline__ TDec decode_target(const float* __restrict__ tgt, int b, int n){
    const float aw[9] = {116.f/416.f,156.f/416.f,373.f/416.f, 30.f/416.f, 62.f/416.f,
                          59.f/416.f, 10.f/416.f, 16.f/416.f, 33.f/416.f};
    const float ah[9] = { 90.f/416.f,198.f/416.f,326.f/416.f, 61.f/416.f, 45.f/416.f,
                         119.f/416.f, 13.f/416.f, 30.f/416.f, 23.f/416.f};
    const float* t = tgt + (b*NT + n)*5;
    float cx = t[0], cy = t[1], w = t[2], h = t[3];
    TDec d;
    d.cls = (int)t[4];
    d.w = w; d.h = h;
    float wh = w*h;
    int best = 0; float bi = -1.f, baw = aw[0], bah = ah[0];
    #pragma unroll
    for (int k = 0; k < 9; ++k){
        float inter = fminf(w, aw[k]) * fminf(h, ah[k]);
        float uni   = wh + aw[k]*ah[k] - inter;
        float r     = inter / uni;
        if (r > bi){ bi = r; best = k; baw = aw[k]; bah = ah[k]; }  // first-max wins
    }
    d.lvl = best / 3;
    d.a   = best - d.lvl*3;
    d.F   = (d.lvl==0) ? 13 : (d.lvl==1 ? 26 : 52);
    d.FF  = d.F * d.F;
    d.off = (d.lvl==0) ? 0 : (d.lvl==1 ? S13 : (S13+S26));
    float fx = cx * (float)d.F, fy = cy * (float)d.F;
    d.gx = (int)floorf(fx); d.gy = (int)floorf(fy);
    d.tx = fx - (float)d.gx; d.ty = fy - (float)d.gy;
    d.tw = logf(w / baw);   // 3200 evals total — precise is fine
    d.th = logf(h / bah);
    return d;
}

// ---- dense helpers: sum softplus/square over channels 0..4 of every anchor block ----
template<int FF, int LVL>
__device__ __forceinline__ void dense_scalar(const float* __restrict__ feat, int gb, float* sacc){
    constexpr int elems = NB*3*5*FF;
    constexpr int cFF = 5*FF;
    float s0=0.f,s1=0.f,s2=0.f,s3=0.f,s4=0.f;
    for (int i = gb*256 + (int)threadIdx.x; i < elems; i += DN_BLOCKS*256){
        int ba = i / cFF;              // compile-time divisor -> mul/shift
        int r  = i - ba*cFF;
        int c  = r / FF;
        float v = feat[ba*85*FF + r];
        if      (c == 0) s0 += softplusf(v);
        else if (c == 1) s1 += softplusf(v);
        else if (c == 2) s2 += v*v;
        else if (c == 3) s3 += v*v;
        else             s4 += softplusf(v);
    }
    float vals[5] = {s0,s1,s2,s3,s4};
    int lane = threadIdx.x & 63;
    #pragma unroll
    for (int k = 0; k < 5; ++k){
        float v = vals[k];
        #pragma unroll
        for (int o = 32; o > 0; o >>= 1) v += __shfl_down(v, o);
        if (lane == 0) atomicAdd(&sacc[LVL*16 + k], v);
    }
}

template<int FF, int LVL>
__device__ __forceinline__ void dense_vec4(const float* __restrict__ feat, int gb, float* sacc){
    static_assert(FF % 4 == 0, "");
    constexpr int e4   = NB*3*5*FF/4;
    constexpr int cFF4 = 5*FF/4;
    constexpr int qFF  = FF/4;
    const float4* f4 = (const float4*)feat;
    float s0=0.f,s1=0.f,s2=0.f,s3=0.f,s4=0.f;
    for (int i = gb*256 + (int)threadIdx.x; i < e4; i += DN_BLOCKS*256){
        int ba = i / cFF4;
        int r  = i - ba*cFF4;
        int c  = r / qFF;
        float4 v = f4[ba*(85*FF/4) + r];
        if (c == 2 || c == 3){
            float sq = v.x*v.x + v.y*v.y + v.z*v.z + v.w*v.w;
            if (c == 2) s2 += sq; else s3 += sq;
        } else {
            float sp = softplusf(v.x)+softplusf(v.y)+softplusf(v.z)+softplusf(v.w);
            if (c == 0) s0 += sp; else if (c == 1) s1 += sp; else s4 += sp;
        }
    }
    float vals[5] = {s0,s1,s2,s3,s4};
    int lane = threadIdx.x & 63;
    #pragma unroll
    for (int k = 0; k < 5; ++k){
        float v = vals[k];
        #pragma unroll
        for (int o = 32; o > 0; o >>= 1) v += __shfl_down(v, o);
        if (lane == 0) atomicAdd(&sacc[LVL*16 + k], v);
    }
}

__global__ __launch_bounds__(256) void k_fused(const float* __restrict__ p13,
                                              const float* __restrict__ p26,
                                              const float* __restrict__ p52,
                                              const float* __restrict__ tgt){
    __shared__ float sacc[48];
    int tid = threadIdx.x;
    if (tid < 48) sacc[tid] = 0.f;
    __syncthreads();

    if (blockIdx.x < PB_BLOCKS){
        // ---------- sparse path: 4 blocks per image ----------
        __shared__ int   skey[NT];
        __shared__ int   scb [NT];
        __shared__ int   slvl[NT];
        __shared__ int   scls[NT];
        __shared__ float sf  [NT][6];   // tx,ty,tw,th,w,h
        __shared__ unsigned char swin[NT];
        int b = blockIdx.x >> 2, q = blockIdx.x & 3;
        if (tid < NT){
            TDec d = decode_target(tgt, b, tid);
            int flat = ((b*3 + d.a)*d.F + d.gy)*d.F + d.gx;
            skey[tid] = d.off + flat;
            scb [tid] = ((b*3 + d.a)*85)*d.FF + d.gy*d.F + d.gx;
            slvl[tid] = d.lvl; scls[tid] = d.cls;
            sf[tid][0]=d.tx; sf[tid][1]=d.ty; sf[tid][2]=d.tw;
            sf[tid][3]=d.th; sf[tid][4]=d.w;  sf[tid][5]=d.h;
        }
        __syncthreads();
        if (tid < NT){
            int k = skey[tid]; unsigned char wn = 1;
            for (int m = tid+1; m < NT; ++m) if (skey[m] == k){ wn = 0; break; }  // last-writer wins
            swin[tid] = wn;
        }
        __syncthreads();

        int lane = tid & 63, wv = tid >> 6;
        int n0 = q*13, n1 = (n0+13 < NT) ? n0+13 : NT;
        for (int n = n0 + wv; n < n1; n += 4){
            int lvl = slvl[n];
            const float* feat = (lvl==0) ? p13 : (lvl==1 ? p26 : p52);
            int FF = (lvl==0) ? 169 : (lvl==1 ? 676 : 2704);
            int cb = scb[n];
            int cls = scls[n];
            if (!swin[n]){
                if (lane == 0){
                    float zcl = feat[cb + (5+cls)*FF];   // loser still sets cls_t at winner cell
                    atomicAdd(&sacc[lvl*16 + A_CZ], zcl);
                }
                continue;
            }
            // 85 channels at stride FF: ch=lane (0..63) + ch=64+lane (lane<21)
            float v1 = feat[cb + lane*FF];
            float v2 = (lane < 21) ? feat[cb + (64+lane)*FF] : 0.f;
            float csum = (lane >= 5) ? softplusf(v1) : 0.f;
            if (lane < 21) csum += softplusf(v2);
            #pragma unroll
            for (int o = 32; o > 0; o >>= 1) csum += __shfl_down(csum, o);
            float zx = __shfl(v1, 0), zy = __shfl(v1, 1);
            float pw = __shfl(v1, 2), ph = __shfl(v1, 3), zc = __shfl(v1, 4);
            int ch = 5 + cls;
            float zcl = (ch < 64) ? __shfl(v1, ch) : __shfl(v2, ch - 64);
            if (lane == 0){
                float* acc = &sacc[lvl*16];
                float tx=sf[n][0], ty=sf[n][1], tw=sf[n][2], th=sf[n][3], w=sf[n][4], h=sf[n][5];
                atomicAdd(&acc[A_CZ ], zcl);
                atomicAdd(&acc[A_TXZ], tx*zx);
                atomicAdd(&acc[A_TYZ], ty*zy);
                atomicAdd(&acc[A_TW ], tw*tw - 2.f*pw*tw);
                atomicAdd(&acc[A_TH ], th*th - 2.f*ph*th);
                atomicAdd(&acc[A_ZC ], zc);
                atomicAdd(&acc[A_SSC], 2.f - w*h);
                atomicAdd(&acc[A_NOB], 1.f);
                atomicAdd(&acc[A_CSP], csum);
            }
        }
    } else {
        // ---------- dense path ----------
        int gb = blockIdx.x - PB_BLOCKS;
        dense_scalar< 169,0>(p13, gb, sacc);
        dense_vec4  < 676,1>(p26, gb, sacc);
        dense_vec4  <2704,2>(p52, gb, sacc);
    }
    __syncthreads();
    if (tid < 48) g_partT[tid][blockIdx.x] = sacc[tid];   // plain store; kernel boundary = fence
}

__global__ __launch_bounds__(256) void k_final(float* __restrict__ out){
    __shared__ float bins[48];
    int lane = threadIdx.x & 63, wv = threadIdx.x >> 6;   // 4 waves
    for (int slot = wv; slot < 48; slot += 4){
        float s = 0.f;
        #pragma unroll
        for (int k = 0; k < NBLK/64; ++k) s += g_partT[slot][k*64 + lane];  // coalesced
        #pragma unroll
        for (int o = 32; o > 0; o >>= 1) s += __shfl_down(s, o);
        if (lane == 0) bins[slot] = s;
    }
    __syncthreads();
    if (threadIdx.x == 0){
        float total = 0.f, ntot = 0.f;
        const int sizes[3] = {S13, S26, S52};
        #pragma unroll
        for (int l = 0; l < 3; ++l){
            const float* a = &bins[l*16];
            float size = (float)sizes[l];
            float ssc  = a[A_SSC];
            float lx = (a[A_SPX] - a[A_TXZ]) / size * ssc;
            float ly = (a[A_SPY] - a[A_TYZ]) / size * ssc;
            float lw = (a[A_SW2] + a[A_TW ]) / size * (0.5f*ssc);
            float lh = (a[A_SH2] + a[A_TH ]) / size * (0.5f*ssc);
            float lc = a[A_SPC] - a[A_ZC];       // bce_c*(sum obj + sum noobj) == bce_c*size
            float lcls = (a[A_CSP] - a[A_CZ]) / (a[A_NOB]*(float)NC);
            total += lx + ly + lw + lh + lc + 5.f*lcls;
            ntot  += a[A_NOB];
        }
        out[0] = total / ntot;
    }
}

extern "C" void kernel_launch(void* const* d_in, const int* in_sizes, int n_in,
                              void* d_out, int out_size, void* d_ws, size_t ws_size,
                              hipStream_t stream){
    const float* p13 = (const float*)d_in[0];
    const float* p26 = (const float*)d_in[1];
    const float* p52 = (const float*)d_in[2];
    const float* tgt = (const float*)d_in[3];
    float* out = (float*)d_out;

    k_fused<<<NBLK, 256, 0, stream>>>(p13, p26, p52, tgt);
    k_final<<<1, 256, 0, stream>>>(out);
}